// Round 3
// baseline (1321.391 us; speedup 1.0000x reference)
//
#include <hip/hip_runtime.h>
#include <hip/hip_bf16.h>

// HINGE_56985626083396 — fused embedding-conv-BN-min-FC forward on MI355X.
//
// All float tensors are FP32 per the reference (round-2 NaN came from reading
// f32 tables as bf16: random mantissa low-halves decode as Inf/NaN bf16 ->
// var=Inf -> c=NaN). MFMA needs bf16, so weights (always) and embedding
// tables (if ws_size permits, ~87 MB) are pre-converted to bf16 each call;
// otherwise A-staging converts f32->bf16 on the fly (template flag CVTA).
//
// Passes:
//   W-convert (+ optional emb-convert)
//   A: GEMM1+GEMM2 with sum/sumsq epilogue (BN stats only, nothing stored)
//   B: fold stats + gamma/beta into per-(window,f) affine (a,c)
//   C: GEMM1 recompute -> affine+relu+min over windows {0,1} -> min1[b][f] bf16
//   D: GEMM2 recompute -> affine+relu+min windows {2..5} + min1 -> fc dot
//      -> atomicAdd outacc[b]
//   E: out[b] = outacc[b] + fc_b   (fp32 out)
// conv biases are skipped: BN mean-subtraction cancels them exactly.

typedef __hip_bfloat16 bf16;
typedef short bf16x8 __attribute__((ext_vector_type(8)));   // 8 bf16 in 4 VGPRs
typedef float f32x4 __attribute__((ext_vector_type(4)));

#define BATCH 32768
#define MODE_STATS 0
#define MODE_MIN1  1
#define MODE_FINAL 2

__device__ __forceinline__ unsigned short f2b(float f) {
    union { float f; unsigned u; } v; v.f = f;
    unsigned r = v.u + 0x7fffu + ((v.u >> 16) & 1u);   // round-to-nearest-even
    return (unsigned short)(r >> 16);
}

__global__ __launch_bounds__(256)
void cvt_kernel(const float* __restrict__ src, unsigned short* __restrict__ dst, int n4)
{
    int i = blockIdx.x * 256 + threadIdx.x;
    if (i >= n4) return;
    float4 v = ((const float4*)src)[i];
    ushort4 h;
    h.x = f2b(v.x); h.y = f2b(v.y); h.z = f2b(v.z); h.w = f2b(v.w);
    ((ushort4*)dst)[i] = h;
}

// out[m, f] = sum_k A[m,k] * W[f,k];  A rows gathered from embedding tables:
// row m -> (b = m/RPB, kk = m%RPB), K split into 256-wide segments (one
// embedding vector each). 128x128 tile per block, BK=64.
// CVTA: embedding tables are f32 (convert during staging); else bf16.
template<int KLEN, int RPB, int MODE, bool CVTA>
__global__ __launch_bounds__(256)
void gemm_kernel(const int* __restrict__ x, const void* __restrict__ embR_,
                 const void* __restrict__ embV_, const bf16* __restrict__ W,
                 float* __restrict__ accum, const float* __restrict__ coef,
                 bf16* __restrict__ min1, const float* __restrict__ fcw,
                 float* __restrict__ outacc)
{
    constexpr int KOFF = (RPB == 2) ? 0 : 2;
    __shared__ __align__(16) short Ash[128 * 72];   // +8 pad breaks bank stride
    __shared__ __align__(16) short Bsh[128 * 72];
    constexpr int NB = 128 / RPB;                   // batch elems per tile
    __shared__ int xsh[NB * 12];
    __shared__ float red[1024];                     // stats: RPB*128 sums+sumsq

    const int tid = threadIdx.x;
    const int m_base = blockIdx.x * 128;
    const int n_base = blockIdx.y * 128;
    const int b0 = m_base / RPB;

    for (int i = tid; i < NB * 12; i += 256) xsh[i] = x[b0 * 12 + i];
    __syncthreads();

    const int lane = tid & 63;
    const int wv   = tid >> 6;                  // wave 0..3, 2x2 of 64x64
    const int wmb  = (wv >> 1) * 64;
    const int wnb  = (wv & 1) * 64;
    const int quad = lane >> 4;
    const int l16  = lane & 15;

    f32x4 acc[4][4];
    #pragma unroll
    for (int i = 0; i < 4; ++i)
        #pragma unroll
        for (int j = 0; j < 4; ++j)
            acc[i][j] = (f32x4){0.f, 0.f, 0.f, 0.f};

    constexpr int NCH = KLEN / 64;
    for (int ch = 0; ch < NCH; ++ch) {
        const int k0  = ch * 64;
        const int seg = k0 >> 8;                // which 256-elem segment

        // ---- stage A: 128 rows x 64 k ----
        auto pick = [&](int row, int& idx, int& isRole) {
            if constexpr (RPB == 2) {
                int bl = row >> 1, kk = row & 1;
                if (seg == 0) { idx = xsh[bl * 12 + 2 * kk + 1]; isRole = 0; }
                else          { idx = xsh[bl * 12 + 0];          isRole = 1; }
            } else {
                int bl = row >> 2, kk = row & 3;
                switch (seg) {
                    case 0:  idx = xsh[bl * 12 + 1];          isRole = 0; break;
                    case 1:  idx = xsh[bl * 12 + 0];          isRole = 1; break;
                    case 2:  idx = xsh[bl * 12 + 3];          isRole = 0; break;
                    case 3:  idx = xsh[bl * 12 + 2 * kk + 4]; isRole = 1; break;
                    default: idx = xsh[bl * 12 + 2 * kk + 5]; isRole = 0; break;
                }
            }
        };
        if constexpr (CVTA) {
            const float* embRf = (const float*)embR_;
            const float* embVf = (const float*)embV_;
            const int so4 = (k0 & 255) >> 2;    // float4 offset within segment
            #pragma unroll
            for (int i = 0; i < 8; ++i) {
                int flat = tid + i * 256;       // 0..2047
                int row  = flat >> 4;
                int off4 = flat & 15;
                int idx, isRole;
                pick(row, idx, isRole);
                const float* tab = isRole ? embRf : embVf;
                float4 v = ((const float4*)(tab + (size_t)idx * 256))[so4 + off4];
                ushort4 h;
                h.x = f2b(v.x); h.y = f2b(v.y); h.z = f2b(v.z); h.w = f2b(v.w);
                *(ushort4*)&Ash[row * 72 + off4 * 4] = h;
            }
        } else {
            const bf16* embRb = (const bf16*)embR_;
            const bf16* embVb = (const bf16*)embV_;
            const int so8 = (k0 & 255) >> 3;    // uint4(8xbf16) offset in seg
            #pragma unroll
            for (int i = 0; i < 4; ++i) {
                int flat = tid + i * 256;       // 0..1023
                int row  = flat >> 3;
                int off8 = flat & 7;
                int idx, isRole;
                pick(row, idx, isRole);
                const bf16* tab = isRole ? embRb : embVb;
                uint4 v = ((const uint4*)(tab + (size_t)idx * 256))[so8 + off8];
                *(uint4*)&Ash[row * 72 + off8 * 8] = v;
            }
        }
        // ---- stage B: W rows f in [n_base, n_base+128), k-chunk [k0,k0+64) ----
        #pragma unroll
        for (int i = 0; i < 4; ++i) {
            int flat = tid + i * 256;
            int fr   = flat >> 3;
            int off8 = flat & 7;
            uint4 v = ((const uint4*)(W + (size_t)(n_base + fr) * KLEN + k0))[off8];
            *(uint4*)&Bsh[fr * 72 + off8 * 8] = v;
        }
        __syncthreads();

        #pragma unroll
        for (int ks = 0; ks < 64; ks += 32) {
            bf16x8 af[4], bf_[4];
            #pragma unroll
            for (int t = 0; t < 4; ++t)
                af[t]  = *(const bf16x8*)&Ash[(wmb + t * 16 + l16) * 72 + ks + quad * 8];
            #pragma unroll
            for (int t = 0; t < 4; ++t)
                bf_[t] = *(const bf16x8*)&Bsh[(wnb + t * 16 + l16) * 72 + ks + quad * 8];
            #pragma unroll
            for (int i = 0; i < 4; ++i)
                #pragma unroll
                for (int j = 0; j < 4; ++j)
                    acc[i][j] = __builtin_amdgcn_mfma_f32_16x16x32_bf16(
                        af[i], bf_[j], acc[i][j], 0, 0, 0);
        }
        __syncthreads();
    }

    // ---- epilogue. C/D layout: f(col) = lane&15, m(row) = quad*4 + reg,
    // so m = m_base + wmb + i*16 + quad*4 + r  (m % RPB == r % RPB),
    // f = n_base + wnb + j*16 + l16.
    if constexpr (MODE == MODE_STATS) {
        for (int i = tid; i < RPB * 256; i += 256) red[i] = 0.f;
        __syncthreads();
        #pragma unroll
        for (int j = 0; j < 4; ++j) {
            int fl = wnb + j * 16 + l16;
            #pragma unroll
            for (int r = 0; r < 4; ++r) {
                int kk = r % RPB;
                float s = 0.f, q = 0.f;
                #pragma unroll
                for (int i = 0; i < 4; ++i) {
                    float v = acc[i][j][r];
                    s += v; q += v * v;
                }
                atomicAdd(&red[kk * 128 + fl], s);
                atomicAdd(&red[RPB * 128 + kk * 128 + fl], q);
            }
        }
        __syncthreads();
        for (int idx = tid; idx < RPB * 128; idx += 256) {
            int kw = KOFF + (idx >> 7);
            int f  = n_base + (idx & 127);
            atomicAdd(&accum[kw * 512 + f], red[idx]);
            atomicAdd(&accum[3072 + kw * 512 + f], red[RPB * 128 + idx]);
        }
    } else if constexpr (MODE == MODE_MIN1) {
        #pragma unroll
        for (int j = 0; j < 4; ++j) {
            int f = n_base + wnb + j * 16 + l16;
            float a0 = coef[f],        c0 = coef[3072 + f];
            float a1 = coef[512 + f],  c1 = coef[3072 + 512 + f];
            #pragma unroll
            for (int i = 0; i < 4; ++i) {
                #pragma unroll
                for (int rp = 0; rp < 2; ++rp) {
                    int m = m_base + wmb + i * 16 + quad * 4 + rp * 2;
                    float v0 = fmaxf(a0 * acc[i][j][rp * 2]     + c0, 0.f);
                    float v1 = fmaxf(a1 * acc[i][j][rp * 2 + 1] + c1, 0.f);
                    unsigned short hb = f2b(fminf(v0, v1));
                    *(unsigned short*)&min1[(size_t)(m >> 1) * 512 + f] = hb;
                }
            }
        }
    } else {  // MODE_FINAL: RPB==4, windows 2..5 in r=0..3 of each (i,j)
        float dotp[4] = {0.f, 0.f, 0.f, 0.f};
        #pragma unroll
        for (int j = 0; j < 4; ++j) {
            int f = n_base + wnb + j * 16 + l16;
            float a[4], c[4];
            #pragma unroll
            for (int r = 0; r < 4; ++r) {
                a[r] = coef[(2 + r) * 512 + f];
                c[r] = coef[3072 + (2 + r) * 512 + f];
            }
            float fw = fcw[f];
            #pragma unroll
            for (int i = 0; i < 4; ++i) {
                int b = b0 + (wmb >> 2) + i * 4 + quad;
                float mv = 1e30f;
                #pragma unroll
                for (int r = 0; r < 4; ++r)
                    mv = fminf(mv, fmaxf(a[r] * acc[i][j][r] + c[r], 0.f));
                mv = fminf(mv, __bfloat162float(min1[(size_t)b * 512 + f]));
                dotp[i] += mv * fw;
            }
        }
        // reduce over the 16 lanes sharing quad (same b; f spread over l16)
        #pragma unroll
        for (int i = 0; i < 4; ++i) {
            float v = dotp[i];
            #pragma unroll
            for (int s = 8; s >= 1; s >>= 1) v += __shfl_xor(v, s);
            if (l16 == 0) {
                int b = b0 + (wmb >> 2) + i * 4 + quad;
                atomicAdd(&outacc[b], v);
            }
        }
    }
}

// Fold BN stats + gamma/beta into affine y = a*x + c per (kw,f).
__global__ void bncoef_kernel(const float* __restrict__ accum,
                              const float* __restrict__ g1, const float* __restrict__ be1,
                              const float* __restrict__ g2, const float* __restrict__ be2,
                              float* __restrict__ coef)
{
    int id = blockIdx.x * 256 + threadIdx.x;
    if (id >= 3072) return;
    int kw = id >> 9, f = id & 511;
    float mean = accum[id] * (1.f / BATCH);
    float var  = accum[3072 + id] * (1.f / BATCH) - mean * mean;
    float g  = kw < 2 ? g1[f] : g2[f];
    float be = kw < 2 ? be1[f] : be2[f];
    float a  = g * rsqrtf(var + 1e-5f);
    coef[id] = a;
    coef[3072 + id] = be - a * mean;
}

__global__ void finish_kernel(const float* __restrict__ outacc,
                              const float* __restrict__ fcb, float* __restrict__ out)
{
    int b = blockIdx.x * 256 + threadIdx.x;
    if (b < BATCH)
        out[b] = outacc[b] + fcb[0];
}

extern "C" void kernel_launch(void* const* d_in, const int* in_sizes, int n_in,
                              void* d_out, int out_size, void* d_ws, size_t ws_size,
                              hipStream_t stream)
{
    (void)in_sizes; (void)n_in; (void)out_size;
    const int*   x    = (const int*)  d_in[0];
    // d_in[1] = arity (fixed 6); d_in[5]/d_in[9] conv biases cancel under BN.
    const float* embR = (const float*)d_in[2];    // 50000 x 256 f32
    const float* embV = (const float*)d_in[3];    // 50000 x 256 f32
    const float* W1   = (const float*)d_in[4];    // 512 x 2 x 256 f32
    const float* g1   = (const float*)d_in[6];
    const float* be1  = (const float*)d_in[7];
    const float* W2   = (const float*)d_in[8];    // 512 x 5 x 256 f32
    const float* g2   = (const float*)d_in[10];
    const float* be2  = (const float*)d_in[11];
    const float* fcw  = (const float*)d_in[12];   // 1 x 512 f32
    const float* fcb  = (const float*)d_in[13];

    char* wsb = (char*)d_ws;
    float* accum  = (float*)wsb;                          // 6144 f (sum|sumsq)
    float* coef   = accum + 6144;                         // 6144 f (a|c)
    float* outacc = coef + 6144;                          // 32768 f
    bf16*  min1   = (bf16*)(wsb + 180224);                // B*512 bf16 = 33.55 MB
    bf16*  Wbf1   = (bf16*)(wsb + 33734656);              // 512 KB
    bf16*  Wbf2   = (bf16*)(wsb + 34258944);              // 1.31 MB
    bf16*  embRb  = (bf16*)(wsb + 35569664);              // 25.6 MB
    bf16*  embVb  = (bf16*)(wsb + 61169664);              // 25.6 MB
    const bool pre = ws_size >= 86769664;                 // emb pre-convert fits?

    hipMemsetAsync(accum, 0, 6144 * sizeof(float), stream);
    hipMemsetAsync(outacc, 0, BATCH * sizeof(float), stream);

    cvt_kernel<<<(65536 + 255) / 256, 256, 0, stream>>>(W1, (unsigned short*)Wbf1, 65536);
    cvt_kernel<<<(163840 + 255) / 256, 256, 0, stream>>>(W2, (unsigned short*)Wbf2, 163840);

    if (pre) {
        cvt_kernel<<<12500, 256, 0, stream>>>(embR, (unsigned short*)embRb, 3200000);
        cvt_kernel<<<12500, 256, 0, stream>>>(embV, (unsigned short*)embVb, 3200000);
        gemm_kernel<512, 2, MODE_STATS, false><<<dim3(512, 4), 256, 0, stream>>>(
            x, embRb, embVb, Wbf1, accum, nullptr, nullptr, nullptr, nullptr);
        gemm_kernel<1280, 4, MODE_STATS, false><<<dim3(1024, 4), 256, 0, stream>>>(
            x, embRb, embVb, Wbf2, accum, nullptr, nullptr, nullptr, nullptr);
        bncoef_kernel<<<12, 256, 0, stream>>>(accum, g1, be1, g2, be2, coef);
        gemm_kernel<512, 2, MODE_MIN1, false><<<dim3(512, 4), 256, 0, stream>>>(
            x, embRb, embVb, Wbf1, nullptr, coef, min1, nullptr, nullptr);
        gemm_kernel<1280, 4, MODE_FINAL, false><<<dim3(1024, 4), 256, 0, stream>>>(
            x, embRb, embVb, Wbf2, nullptr, coef, min1, fcw, outacc);
    } else {
        gemm_kernel<512, 2, MODE_STATS, true><<<dim3(512, 4), 256, 0, stream>>>(
            x, embR, embV, Wbf1, accum, nullptr, nullptr, nullptr, nullptr);
        gemm_kernel<1280, 4, MODE_STATS, true><<<dim3(1024, 4), 256, 0, stream>>>(
            x, embR, embV, Wbf2, accum, nullptr, nullptr, nullptr, nullptr);
        bncoef_kernel<<<12, 256, 0, stream>>>(accum, g1, be1, g2, be2, coef);
        gemm_kernel<512, 2, MODE_MIN1, true><<<dim3(512, 4), 256, 0, stream>>>(
            x, embR, embV, Wbf1, nullptr, coef, min1, nullptr, nullptr);
        gemm_kernel<1280, 4, MODE_FINAL, true><<<dim3(1024, 4), 256, 0, stream>>>(
            x, embR, embV, Wbf2, nullptr, coef, min1, fcw, outacc);
    }
    finish_kernel<<<128, 256, 0, stream>>>(outacc, fcb, (float*)d_out);
}

// Round 4
// 969.040 us; speedup vs baseline: 1.3636x; 1.3636x over previous
//
#include <hip/hip_runtime.h>
#include <hip/hip_bf16.h>

// HINGE_56985626083396 — fused embedding-conv-BN-min-FC forward on MI355X.
//
// Round-4: hrt-sharing decomposition. win2_k = [hrt | kr_k | kv_k], hrt
// shared across the 4 wide windows, so:
//   H[b,f] = hrt . W2[:,0:768]        (M=B,  K=768)  computed ONCE, stored bf16
//   T[b,k,f] = [kr_k|kv_k] . W2[:,768:1280] (M=4B, K=512)  run twice (stats+final)
// cuts total MFMA work 44% vs the monolithic K=1280 GEMM run twice.
// conv biases are skipped: BN mean-subtraction cancels them exactly.
//
// ws tiers (ws_size unknown; round 3 proved >= 35.6 MB):
//   tier1 >=120.4 MB: emb tables pre-converted to bf16 (fast staging)
//   tier2 >= 69.2 MB: f32 gather + inline f32->bf16 convert in staging
//   tier3 (fallback): round-3 structure, 35.6 MB, CVTA staging

typedef __hip_bfloat16 bf16;
typedef short bf16x8 __attribute__((ext_vector_type(8)));   // 8 bf16 in 4 VGPRs
typedef float f32x4 __attribute__((ext_vector_type(4)));

#define BATCH 32768
#define MODE_STATS 0
#define MODE_MIN1  1
#define MODE_FINAL 2
#define MODE_STORE 3

__device__ __forceinline__ unsigned short f2b(float f) {
    union { float f; unsigned u; } v; v.f = f;
    unsigned r = v.u + 0x7fffu + ((v.u >> 16) & 1u);   // round-to-nearest-even
    return (unsigned short)(r >> 16);
}

__global__ __launch_bounds__(256)
void cvt_kernel(const float* __restrict__ src, unsigned short* __restrict__ dst, int n4)
{
    int i = blockIdx.x * 256 + threadIdx.x;
    if (i >= n4) return;
    float4 v = ((const float4*)src)[i];
    ushort4 h;
    h.x = f2b(v.x); h.y = f2b(v.y); h.z = f2b(v.z); h.w = f2b(v.w);
    ((ushort4*)dst)[i] = h;
}

// out[m,f] = sum_k A[m,k] * W[f, KWOFF+k],  W rows at stride KSTR (bf16).
// A rows gathered from embeddings; row m -> (b=m/RPB, kk=m%RPB); K in 256-wide
// segments. 128x128 tile, BK=64, 4 waves in 2x2 of 64x64.
// CVTA: embedding tables are f32 (convert during staging) else bf16.
// HADD: add Hbuf[b,f] to accumulator value in STATS/FINAL epilogues.
template<int KLEN, int KSTR, int KWOFF, int RPB, int MODE, bool HADD, bool CVTA>
__global__ __launch_bounds__(256)
void gemm_kernel(const int* __restrict__ x, const void* __restrict__ embR_,
                 const void* __restrict__ embV_, const bf16* __restrict__ W,
                 float* __restrict__ accum, const float* __restrict__ coef,
                 bf16* __restrict__ min1, bf16* __restrict__ Hbuf,
                 const float* __restrict__ fcw, float* __restrict__ outacc)
{
    constexpr int KOFF = (RPB == 2) ? 0 : 2;        // window offset in stats
    __shared__ __align__(16) short Ash[128 * 72];   // +8 pad: frag reads 2-way(free)
    __shared__ __align__(16) short Bsh[128 * 72];
    constexpr int NB = 128 / RPB;
    __shared__ int xsh[NB * 12];
    __shared__ float red[(MODE == MODE_STATS) ? RPB * 256 : 4];

    const int tid = threadIdx.x;
    const int m_base = blockIdx.x * 128;
    const int n_base = blockIdx.y * 128;
    const int b0 = m_base / RPB;

    for (int i = tid; i < NB * 12; i += 256) xsh[i] = x[b0 * 12 + i];
    __syncthreads();

    const int lane = tid & 63;
    const int wv   = tid >> 6;
    const int wmb  = (wv >> 1) * 64;
    const int wnb  = (wv & 1) * 64;
    const int quad = lane >> 4;
    const int l16  = lane & 15;

    f32x4 acc[4][4];
    #pragma unroll
    for (int i = 0; i < 4; ++i)
        #pragma unroll
        for (int j = 0; j < 4; ++j)
            acc[i][j] = (f32x4){0.f, 0.f, 0.f, 0.f};

    constexpr int NCH = KLEN / 64;
    for (int ch = 0; ch < NCH; ++ch) {
        const int k0  = ch * 64;
        const int seg = k0 >> 8;

        auto pick = [&](int row, int& idx, int& isRole) {
            if constexpr (RPB == 1) {               // H: hrt = [fv0|fr0|fv1]
                if      (seg == 0) { idx = xsh[row * 12 + 1]; isRole = 0; }
                else if (seg == 1) { idx = xsh[row * 12 + 0]; isRole = 1; }
                else               { idx = xsh[row * 12 + 3]; isRole = 0; }
            } else if constexpr (RPB == 2) {        // GEMM1: [fv_kk | fr0]
                int bl = row >> 1, kk = row & 1;
                if (seg == 0) { idx = xsh[bl * 12 + 2 * kk + 1]; isRole = 0; }
                else          { idx = xsh[bl * 12 + 0];          isRole = 1; }
            } else if constexpr (KLEN == 512) {     // T: [kr_kk | kv_kk]
                int bl = row >> 2, kk = row & 3;
                if (seg == 0) { idx = xsh[bl * 12 + 2 * kk + 4]; isRole = 1; }
                else          { idx = xsh[bl * 12 + 2 * kk + 5]; isRole = 0; }
            } else {                                // tier3 full win2
                int bl = row >> 2, kk = row & 3;
                switch (seg) {
                    case 0:  idx = xsh[bl * 12 + 1];          isRole = 0; break;
                    case 1:  idx = xsh[bl * 12 + 0];          isRole = 1; break;
                    case 2:  idx = xsh[bl * 12 + 3];          isRole = 0; break;
                    case 3:  idx = xsh[bl * 12 + 2 * kk + 4]; isRole = 1; break;
                    default: idx = xsh[bl * 12 + 2 * kk + 5]; isRole = 0; break;
                }
            }
        };

        if constexpr (CVTA) {
            const float* embRf = (const float*)embR_;
            const float* embVf = (const float*)embV_;
            const int so4 = (k0 & 255) >> 2;
            #pragma unroll
            for (int i = 0; i < 8; ++i) {
                int flat = tid + i * 256;           // 0..2047
                int row  = flat >> 4;
                int off4 = flat & 15;
                int idx, isRole;
                pick(row, idx, isRole);
                const float* tab = isRole ? embRf : embVf;
                float4 v = ((const float4*)(tab + (size_t)idx * 256))[so4 + off4];
                ushort4 h;
                h.x = f2b(v.x); h.y = f2b(v.y); h.z = f2b(v.z); h.w = f2b(v.w);
                *(ushort4*)&Ash[row * 72 + off4 * 4] = h;
            }
        } else {
            const bf16* embRb = (const bf16*)embR_;
            const bf16* embVb = (const bf16*)embV_;
            const int so8 = (k0 & 255) >> 3;
            #pragma unroll
            for (int i = 0; i < 4; ++i) {
                int flat = tid + i * 256;           // 0..1023
                int row  = flat >> 3;
                int off8 = flat & 7;
                int idx, isRole;
                pick(row, idx, isRole);
                const bf16* tab = isRole ? embRb : embVb;
                uint4 v = ((const uint4*)(tab + (size_t)idx * 256))[so8 + off8];
                *(uint4*)&Ash[row * 72 + off8 * 8] = v;
            }
        }
        // stage W rows f in [n_base, n_base+128), k-chunk [KWOFF+k0, +64)
        #pragma unroll
        for (int i = 0; i < 4; ++i) {
            int flat = tid + i * 256;
            int fr   = flat >> 3;
            int off8 = flat & 7;
            uint4 v = ((const uint4*)(W + (size_t)(n_base + fr) * KSTR + KWOFF + k0))[off8];
            *(uint4*)&Bsh[fr * 72 + off8 * 8] = v;
        }
        __syncthreads();

        #pragma unroll
        for (int ks = 0; ks < 64; ks += 32) {
            bf16x8 af[4], bf_[4];
            #pragma unroll
            for (int t = 0; t < 4; ++t)
                af[t]  = *(const bf16x8*)&Ash[(wmb + t * 16 + l16) * 72 + ks + quad * 8];
            #pragma unroll
            for (int t = 0; t < 4; ++t)
                bf_[t] = *(const bf16x8*)&Bsh[(wnb + t * 16 + l16) * 72 + ks + quad * 8];
            #pragma unroll
            for (int i = 0; i < 4; ++i)
                #pragma unroll
                for (int j = 0; j < 4; ++j)
                    acc[i][j] = __builtin_amdgcn_mfma_f32_16x16x32_bf16(
                        af[i], bf_[j], acc[i][j], 0, 0, 0);
        }
        __syncthreads();
    }

    // Epilogues. C/D layout: f(col) = l16, m(row) = quad*4 + reg.
    // m = m_base + wmb + i*16 + quad*4 + r;  f = n_base + wnb + j*16 + l16.
    if constexpr (MODE == MODE_STORE) {             // H store (RPB==1)
        #pragma unroll
        for (int j = 0; j < 4; ++j) {
            int f = n_base + wnb + j * 16 + l16;
            #pragma unroll
            for (int i = 0; i < 4; ++i)
                #pragma unroll
                for (int r = 0; r < 4; ++r) {
                    int m = m_base + wmb + i * 16 + quad * 4 + r;
                    *(unsigned short*)&Hbuf[(size_t)m * 512 + f] = f2b(acc[i][j][r]);
                }
        }
    } else if constexpr (MODE == MODE_STATS) {
        for (int i = tid; i < RPB * 256; i += 256) red[i] = 0.f;
        __syncthreads();
        #pragma unroll
        for (int j = 0; j < 4; ++j) {
            int fl = wnb + j * 16 + l16;
            float sr[4] = {0.f,0.f,0.f,0.f}, qr[4] = {0.f,0.f,0.f,0.f};
            #pragma unroll
            for (int i = 0; i < 4; ++i) {
                float h = 0.f;
                if constexpr (HADD) {               // RPB==4: one b per (i,quad)
                    int b = b0 + (wmb >> 2) + i * 4 + quad;
                    h = __bfloat162float(Hbuf[(size_t)b * 512 + n_base + fl]);
                }
                #pragma unroll
                for (int r = 0; r < 4; ++r) {
                    float v = acc[i][j][r] + h;
                    sr[r] += v; qr[r] += v * v;
                }
            }
            #pragma unroll
            for (int r = 0; r < 4; ++r) {
                int kk = r % RPB;
                atomicAdd(&red[kk * 128 + fl], sr[r]);
                atomicAdd(&red[RPB * 128 + kk * 128 + fl], qr[r]);
            }
        }
        __syncthreads();
        for (int idx = tid; idx < RPB * 128; idx += 256) {
            int kw = KOFF + (idx >> 7);
            int f  = n_base + (idx & 127);
            atomicAdd(&accum[kw * 512 + f], red[idx]);
            atomicAdd(&accum[3072 + kw * 512 + f], red[RPB * 128 + idx]);
        }
    } else if constexpr (MODE == MODE_MIN1) {       // RPB==2, windows 0,1
        #pragma unroll
        for (int j = 0; j < 4; ++j) {
            int f = n_base + wnb + j * 16 + l16;
            float a0 = coef[f],        c0 = coef[3072 + f];
            float a1 = coef[512 + f],  c1 = coef[3072 + 512 + f];
            #pragma unroll
            for (int i = 0; i < 4; ++i) {
                #pragma unroll
                for (int rp = 0; rp < 2; ++rp) {
                    int m = m_base + wmb + i * 16 + quad * 4 + rp * 2;
                    float v0 = fmaxf(a0 * acc[i][j][rp * 2]     + c0, 0.f);
                    float v1 = fmaxf(a1 * acc[i][j][rp * 2 + 1] + c1, 0.f);
                    *(unsigned short*)&min1[(size_t)(m >> 1) * 512 + f] =
                        f2b(fminf(v0, v1));
                }
            }
        }
    } else {  // MODE_FINAL: RPB==4, windows 2..5 in r=0..3
        float dotp[4] = {0.f, 0.f, 0.f, 0.f};
        #pragma unroll
        for (int j = 0; j < 4; ++j) {
            int f = n_base + wnb + j * 16 + l16;
            float a[4], c[4];
            #pragma unroll
            for (int r = 0; r < 4; ++r) {
                a[r] = coef[(2 + r) * 512 + f];
                c[r] = coef[3072 + (2 + r) * 512 + f];
            }
            float fw = fcw[f];
            #pragma unroll
            for (int i = 0; i < 4; ++i) {
                int b = b0 + (wmb >> 2) + i * 4 + quad;
                float h = 0.f;
                if constexpr (HADD)
                    h = __bfloat162float(Hbuf[(size_t)b * 512 + f]);
                float mv = 1e30f;
                #pragma unroll
                for (int r = 0; r < 4; ++r)
                    mv = fminf(mv, fmaxf(a[r] * (acc[i][j][r] + h) + c[r], 0.f));
                mv = fminf(mv, __bfloat162float(min1[(size_t)b * 512 + f]));
                dotp[i] += mv * fw;
            }
        }
        #pragma unroll
        for (int i = 0; i < 4; ++i) {
            float v = dotp[i];
            #pragma unroll
            for (int s = 8; s >= 1; s >>= 1) v += __shfl_xor(v, s);
            if (l16 == 0) {
                int b = b0 + (wmb >> 2) + i * 4 + quad;
                atomicAdd(&outacc[b], v);
            }
        }
    }
}

__global__ void bncoef_kernel(const float* __restrict__ accum,
                              const float* __restrict__ g1, const float* __restrict__ be1,
                              const float* __restrict__ g2, const float* __restrict__ be2,
                              float* __restrict__ coef)
{
    int id = blockIdx.x * 256 + threadIdx.x;
    if (id >= 3072) return;
    int kw = id >> 9, f = id & 511;
    float mean = accum[id] * (1.f / BATCH);
    float var  = accum[3072 + id] * (1.f / BATCH) - mean * mean;
    float g  = kw < 2 ? g1[f] : g2[f];
    float be = kw < 2 ? be1[f] : be2[f];
    float a  = g * rsqrtf(var + 1e-5f);
    coef[id] = a;
    coef[3072 + id] = be - a * mean;
}

__global__ void finish_kernel(const float* __restrict__ outacc,
                              const float* __restrict__ fcb, float* __restrict__ out)
{
    int b = blockIdx.x * 256 + threadIdx.x;
    if (b < BATCH)
        out[b] = outacc[b] + fcb[0];
}

extern "C" void kernel_launch(void* const* d_in, const int* in_sizes, int n_in,
                              void* d_out, int out_size, void* d_ws, size_t ws_size,
                              hipStream_t stream)
{
    (void)in_sizes; (void)n_in; (void)out_size;
    const int*   x    = (const int*)  d_in[0];
    const float* embR = (const float*)d_in[2];    // 50000 x 256 f32
    const float* embV = (const float*)d_in[3];    // 50000 x 256 f32
    const float* W1   = (const float*)d_in[4];    // 512 x 2 x 256 f32
    const float* g1   = (const float*)d_in[6];
    const float* be1  = (const float*)d_in[7];
    const float* W2   = (const float*)d_in[8];    // 512 x 5 x 256 f32
    const float* g2   = (const float*)d_in[10];
    const float* be2  = (const float*)d_in[11];
    const float* fcw  = (const float*)d_in[12];   // 512 f32
    const float* fcb  = (const float*)d_in[13];

    char* wsb = (char*)d_ws;
    float* accum  = (float*)wsb;                          //       0: 24 KB
    float* coef   = accum + 6144;                         //   24576: 24 KB
    float* outacc = coef + 6144;                          //   49152: 128 KB
    bf16*  Wbf1   = (bf16*)(wsb + 180224);                //  512 KB
    bf16*  Wbf2   = (bf16*)(wsb + 704512);                // 1.25 MB
    bf16*  Hbuf   = (bf16*)(wsb + 2015232);               // 32 MB (B*512 bf16)
    bf16*  min1   = (bf16*)(wsb + 35569664);              // 32 MB -> ends 69124096
    bf16*  embRb  = (bf16*)(wsb + 69124096);              // 24.4 MB
    bf16*  embVb  = (bf16*)(wsb + 94724096);              // ends 120324096
    bf16*  min3   = (bf16*)(wsb + 2015232);               // tier3 min1 (H slot)

    const int tier = (ws_size >= 120324096) ? 1 : (ws_size >= 69124096) ? 2 : 3;

    hipMemsetAsync(accum, 0, 6144 * sizeof(float), stream);
    hipMemsetAsync(outacc, 0, BATCH * sizeof(float), stream);
    cvt_kernel<<<256, 256, 0, stream>>>(W1, (unsigned short*)Wbf1, 65536);
    cvt_kernel<<<640, 256, 0, stream>>>(W2, (unsigned short*)Wbf2, 163840);

    if (tier == 1) {
        cvt_kernel<<<12500, 256, 0, stream>>>(embR, (unsigned short*)embRb, 3200000);
        cvt_kernel<<<12500, 256, 0, stream>>>(embV, (unsigned short*)embVb, 3200000);
        gemm_kernel<768, 1280, 0, 1, MODE_STORE, false, false><<<dim3(256, 4), 256, 0, stream>>>(
            x, embRb, embVb, Wbf2, nullptr, nullptr, nullptr, Hbuf, nullptr, nullptr);
        gemm_kernel<512, 512, 0, 2, MODE_STATS, false, false><<<dim3(512, 4), 256, 0, stream>>>(
            x, embRb, embVb, Wbf1, accum, nullptr, nullptr, nullptr, nullptr, nullptr);
        gemm_kernel<512, 1280, 768, 4, MODE_STATS, true, false><<<dim3(1024, 4), 256, 0, stream>>>(
            x, embRb, embVb, Wbf2, accum, nullptr, nullptr, Hbuf, nullptr, nullptr);
        bncoef_kernel<<<12, 256, 0, stream>>>(accum, g1, be1, g2, be2, coef);
        gemm_kernel<512, 512, 0, 2, MODE_MIN1, false, false><<<dim3(512, 4), 256, 0, stream>>>(
            x, embRb, embVb, Wbf1, nullptr, coef, min1, nullptr, nullptr, nullptr);
        gemm_kernel<512, 1280, 768, 4, MODE_FINAL, true, false><<<dim3(1024, 4), 256, 0, stream>>>(
            x, embRb, embVb, Wbf2, nullptr, coef, min1, Hbuf, fcw, outacc);
    } else if (tier == 2) {
        gemm_kernel<768, 1280, 0, 1, MODE_STORE, false, true><<<dim3(256, 4), 256, 0, stream>>>(
            x, embR, embV, Wbf2, nullptr, nullptr, nullptr, Hbuf, nullptr, nullptr);
        gemm_kernel<512, 512, 0, 2, MODE_STATS, false, true><<<dim3(512, 4), 256, 0, stream>>>(
            x, embR, embV, Wbf1, accum, nullptr, nullptr, nullptr, nullptr, nullptr);
        gemm_kernel<512, 1280, 768, 4, MODE_STATS, true, true><<<dim3(1024, 4), 256, 0, stream>>>(
            x, embR, embV, Wbf2, accum, nullptr, nullptr, Hbuf, nullptr, nullptr);
        bncoef_kernel<<<12, 256, 0, stream>>>(accum, g1, be1, g2, be2, coef);
        gemm_kernel<512, 512, 0, 2, MODE_MIN1, false, true><<<dim3(512, 4), 256, 0, stream>>>(
            x, embR, embV, Wbf1, nullptr, coef, min1, nullptr, nullptr, nullptr);
        gemm_kernel<512, 1280, 768, 4, MODE_FINAL, true, true><<<dim3(1024, 4), 256, 0, stream>>>(
            x, embR, embV, Wbf2, nullptr, coef, min1, Hbuf, fcw, outacc);
    } else {  // tier3: round-3 proven fallback (35.6 MB)
        gemm_kernel<512, 512, 0, 2, MODE_STATS, false, true><<<dim3(512, 4), 256, 0, stream>>>(
            x, embR, embV, Wbf1, accum, nullptr, nullptr, nullptr, nullptr, nullptr);
        gemm_kernel<1280, 1280, 0, 4, MODE_STATS, false, true><<<dim3(1024, 4), 256, 0, stream>>>(
            x, embR, embV, Wbf2, accum, nullptr, nullptr, nullptr, nullptr, nullptr);
        bncoef_kernel<<<12, 256, 0, stream>>>(accum, g1, be1, g2, be2, coef);
        gemm_kernel<512, 512, 0, 2, MODE_MIN1, false, true><<<dim3(512, 4), 256, 0, stream>>>(
            x, embR, embV, Wbf1, nullptr, coef, min3, nullptr, nullptr, nullptr);
        gemm_kernel<1280, 1280, 0, 4, MODE_FINAL, false, true><<<dim3(1024, 4), 256, 0, stream>>>(
            x, embR, embV, Wbf2, nullptr, coef, min3, nullptr, fcw, outacc);
    }
    finish_kernel<<<128, 256, 0, stream>>>(outacc, fcb, (float*)d_out);
}